// Round 17
// baseline (231.711 us; speedup 1.0000x reference)
//
#include <hip/hip_runtime.h>

#define NN 50000
#define NE 800000

constexpr int H1 = 4, F1 = 128, HC1 = 256;
constexpr int HC2 = 128;
constexpr int GM1 = (NN + 63) / 64;     // 782 gemm blocks
constexpr int GE  = (NE + 255) / 256;   // 3125 edge blocks
constexpr int GN  = (NN + 255) / 256;   // 196 node blocks

typedef unsigned short u16;
typedef unsigned int u32;
typedef __attribute__((ext_vector_type(8))) short bf16x8;
typedef __attribute__((ext_vector_type(4))) float f32x4;

__device__ __forceinline__ float bf2f(u16 h) {
    return __uint_as_float(((u32)h) << 16);
}
__device__ __forceinline__ u16 f2bf(float f) {
    u32 u = __float_as_uint(f);
    u32 r = (u + 0x7fffu + ((u >> 16) & 1u)) >> 16;   // RTN-even
    return (u16)r;
}

__device__ __forceinline__ int ld_edge(const int* e32, const long long* e64, int is64, long long idx) {
    return is64 ? (int)e64[idx] : e32[idx];
}

// ---------------- fused prep:
// [0,128) wp1 | [128,256) wp2 | 256 detect | [257,257+GE) degree count
__global__ __launch_bounds__(256) void k_prep(
    const float* __restrict__ W1, const float* __restrict__ W2,
    u16* __restrict__ wp1, u16* __restrict__ wp2,
    int* __restrict__ deg, const int* __restrict__ e32, const long long* __restrict__ e64,
    int* __restrict__ flag)
{
    const int b = blockIdx.x, tid = threadIdx.x;
    if (b < 128) {                        // wp1: [NK][256][4][8] <- W1[128][256]
        int o = b * 256 + tid;
        int j = o & 7, lk = (o >> 3) & 3, nn = (o >> 5) & 255, kc = o >> 13;
        int k = kc * 32 + lk * 8 + j;
        wp1[o] = f2bf(W1[(size_t)k * HC1 + nn]);
    } else if (b < 256) {                 // wp2: [NK][128][4][8] <- W2[256][128]
        int o = (b - 128) * 256 + tid;
        int j = o & 7, lk = (o >> 3) & 3, nn = (o >> 5) & 127, kc = o >> 12;
        int k = kc * 32 + lk * 8 + j;
        wp2[o] = f2bf(W2[(size_t)k * HC2 + nn]);
    } else if (b == 256) {                // int64 detect (for k_fill)
        if (tid == 0) {
            int z = 1;
            for (int t = 0; t < 16; t++)
                if (e32[2 * t + 1] != 0) z = 0;
            *flag = z;
        }
    } else {                              // degree count (self-detecting is64)
        int e = (b - 257) * 256 + tid;
        if (e < NE) {
            int z = 1;
            #pragma unroll
            for (int t = 0; t < 16; t++) z &= (e32[2 * t + 1] == 0);  // uniform -> scalar loads
            int dst = z ? (int)e64[(long long)NE + e] : e32[(long long)NE + e];
            atomicAdd(&deg[dst], 1);
        }
    }
}

__global__ __launch_bounds__(256) void k_part(const int* __restrict__ deg, int* __restrict__ bsum) {
    int i = blockIdx.x * 256 + threadIdx.x;
    int v = (i < NN) ? deg[i] : 0;
    #pragma unroll
    for (int off = 1; off < 64; off <<= 1) v += __shfl_xor(v, off);
    __shared__ int ws[4];
    if ((threadIdx.x & 63) == 0) ws[threadIdx.x >> 6] = v;
    __syncthreads();
    if (threadIdx.x == 0) bsum[blockIdx.x] = ws[0] + ws[1] + ws[2] + ws[3];
}

// block prefix via in-block masked reduction of bsum (redundant per block, fully parallel)
__global__ __launch_bounds__(256) void k_addb(const int* __restrict__ deg, const int* __restrict__ bsum,
                                              int* __restrict__ row_ptr, int* __restrict__ cursor) {
    const int tid = threadIdx.x;
    const int lane = tid & 63, wv = tid >> 6;
    const int b = blockIdx.x;
    __shared__ int wsum[4], woff[4], s_pref[4], s_tot[4];

    // masked reductions over the GN block sums
    int bs = (tid < GN) ? bsum[tid] : 0;
    int vp = (tid < b) ? bs : 0;          // prefix for this block
    int vt = bs;                          // total
    #pragma unroll
    for (int off = 1; off < 64; off <<= 1) {
        vp += __shfl_xor(vp, off);
        vt += __shfl_xor(vt, off);
    }
    if (lane == 0) { s_pref[wv] = vp; s_tot[wv] = vt; }
    __syncthreads();
    int pref = s_pref[0] + s_pref[1] + s_pref[2] + s_pref[3];
    if (b == 0 && tid == 0)
        row_ptr[NN] = s_tot[0] + s_tot[1] + s_tot[2] + s_tot[3];

    // local exclusive scan of this block's 256 degrees
    int i = b * 256 + tid;
    int v = (i < NN) ? deg[i] : 0;
    int x = v;
    #pragma unroll
    for (int off = 1; off < 64; off <<= 1) {
        int t = __shfl_up(x, off);
        if (lane >= off) x += t;
    }
    if (lane == 63) wsum[wv] = x;
    __syncthreads();
    if (tid == 0) {
        int run = 0;
        #pragma unroll
        for (int j = 0; j < 4; j++) { woff[j] = run; run += wsum[j]; }
    }
    __syncthreads();
    int excl = x - v + woff[wv] + pref;
    if (i < NN) { row_ptr[i] = excl; cursor[i] = excl; }
}

__global__ void k_fill(const int* __restrict__ e32, const long long* __restrict__ e64,
                       const int* __restrict__ flag, int* __restrict__ cursor, int* __restrict__ col) {
    int e = blockIdx.x * blockDim.x + threadIdx.x;
    if (e >= NE) return;
    int is64 = *flag;
    int src = ld_edge(e32, e64, is64, e);
    int dst = ld_edge(e32, e64, is64, (long long)NE + e);
    int pos = atomicAdd(&cursor[dst], 1);
    col[pos] = src;
}

// ---------------- MFMA GEMM body (+ attention-logit epilogue) ----------------
// AF32=1: A is f32, converted to bf16 during staging (TPB must be 256).
template <int K, int NOUT, int HEADS, int TPB, int AF32>
__device__ __forceinline__ void gemm_body(
    int bid, const void* __restrict__ Ain, const u16* __restrict__ Wp,
    const float* __restrict__ atts, const float* __restrict__ attd,
    u16* __restrict__ Hout, float* __restrict__ as_out, float* __restrict__ ad_out, int M)
{
    constexpr int BM = 64, BK = 32;
    constexpr int NK = K / BK;
    constexpr int C = NOUT / HEADS;
    constexpr int LDA = 40;                         // u16 per LDS row (80 B padded)
    __shared__ __align__(16) u16 As[2][BM * LDA];
    __shared__ float red_s[BM * HEADS];
    __shared__ float red_d[BM * HEADS];

    const int tid = threadIdx.x;
    const int w = tid >> 6;
    const int l = tid & 63;
    const int l15 = l & 15, lk = l >> 4;
    const int row0 = bid * BM;
    const int col0 = w * 64;

    for (int i = tid; i < BM * HEADS; i += TPB) { red_s[i] = 0.f; red_d[i] = 0.f; }

    f32x4 acc[4][4];
    #pragma unroll
    for (int rt = 0; rt < 4; rt++)
        #pragma unroll
        for (int nt = 0; nt < 4; nt++)
            acc[rt][nt] = (f32x4){0.f, 0.f, 0.f, 0.f};

    auto stage = [&](int kc, int b) {
        if constexpr (AF32) {
            const float* Af = (const float*)Ain;   // 4 thr/row, 8 f32 each
            int r = tid >> 2, c = (tid & 3) * 8;
            int gr = row0 + r;
            float4 f0 = make_float4(0.f, 0.f, 0.f, 0.f), f1 = f0;
            if (gr < M) {
                f0 = *(const float4*)(Af + (size_t)gr * K + kc * BK + c);
                f1 = *(const float4*)(Af + (size_t)gr * K + kc * BK + c + 4);
            }
            bf16x8 v;
            v[0] = (short)f2bf(f0.x); v[1] = (short)f2bf(f0.y);
            v[2] = (short)f2bf(f0.z); v[3] = (short)f2bf(f0.w);
            v[4] = (short)f2bf(f1.x); v[5] = (short)f2bf(f1.y);
            v[6] = (short)f2bf(f1.z); v[7] = (short)f2bf(f1.w);
            *(bf16x8*)&As[b][r * LDA + c] = v;
        } else {
            const u16* Ab = (const u16*)Ain;
            #pragma unroll
            for (int i = tid; i < BM * 4; i += TPB) {
                int r = i >> 2, c = (i & 3) * 8;
                int gr = row0 + r;
                bf16x8 v = {0, 0, 0, 0, 0, 0, 0, 0};
                if (gr < M) v = *(const bf16x8*)(Ab + (size_t)gr * K + kc * BK + c);
                *(bf16x8*)&As[b][r * LDA + c] = v;
            }
        }
    };
    auto loadB = [&](int kc, bf16x8* bf) {
        #pragma unroll
        for (int nt = 0; nt < 4; nt++)
            bf[nt] = *(const bf16x8*)(Wp + (((size_t)kc * NOUT + col0 + nt * 16 + l15) * 4 + lk) * 8);
    };

    bf16x8 bcur[4];
    loadB(0, bcur);
    stage(0, 0);
    for (int kc = 0; kc < NK; ++kc) {
        __syncthreads();
        bf16x8 afr[4];
        #pragma unroll
        for (int rt = 0; rt < 4; rt++)
            afr[rt] = *(const bf16x8*)&As[kc & 1][(rt * 16 + l15) * LDA + lk * 8];
        bf16x8 bnext[4];
        if (kc + 1 < NK) {
            loadB(kc + 1, bnext);
            stage(kc + 1, (kc + 1) & 1);
        }
        #pragma unroll
        for (int rt = 0; rt < 4; rt++)
            #pragma unroll
            for (int nt = 0; nt < 4; nt++)
                acc[rt][nt] = __builtin_amdgcn_mfma_f32_16x16x32_bf16(afr[rt], bcur[nt], acc[rt][nt], 0, 0, 0);
        if (kc + 1 < NK) {
            #pragma unroll
            for (int nt = 0; nt < 4; nt++) bcur[nt] = bnext[nt];
        }
    }

    // D layout col=l&15, row=(l>>4)*4+t  [m89-verified]
    #pragma unroll
    for (int rt = 0; rt < 4; rt++) {
        #pragma unroll
        for (int t = 0; t < 4; t++) {
            int gr = row0 + rt * 16 + lk * 4 + t;
            if (gr < M) {
                #pragma unroll
                for (int nt = 0; nt < 4; nt++)
                    Hout[(size_t)gr * NOUT + col0 + nt * 16 + l15] = f2bf(acc[rt][nt][t]);
            }
        }
    }

    float avs[4], avd[4];
    #pragma unroll
    for (int nt = 0; nt < 4; nt++) {
        int gc = col0 + nt * 16 + l15;
        avs[nt] = atts[gc];
        avd[nt] = attd[gc];
    }
    const int headw = col0 / C;
    #pragma unroll
    for (int rt = 0; rt < 4; rt++) {
        #pragma unroll
        for (int t = 0; t < 4; t++) {
            float ps = 0.f, pd = 0.f;
            #pragma unroll
            for (int nt = 0; nt < 4; nt++) {
                ps = fmaf(acc[rt][nt][t], avs[nt], ps);
                pd = fmaf(acc[rt][nt][t], avd[nt], pd);
            }
            ps += __shfl_xor(ps, 1); ps += __shfl_xor(ps, 2);
            ps += __shfl_xor(ps, 4); ps += __shfl_xor(ps, 8);
            pd += __shfl_xor(pd, 1); pd += __shfl_xor(pd, 2);
            pd += __shfl_xor(pd, 4); pd += __shfl_xor(pd, 8);
            if (l15 == 0) {
                int row = rt * 16 + lk * 4 + t;
                atomicAdd(&red_s[row * HEADS + headw], ps);
                atomicAdd(&red_d[row * HEADS + headw], pd);
            }
        }
    }
    __syncthreads();
    for (int i = tid; i < BM * HEADS; i += TPB) {
        int gr = row0 + i / HEADS;
        if (gr < M) {
            as_out[(size_t)gr * HEADS + i % HEADS] = red_s[i];
            ad_out[(size_t)gr * HEADS + i % HEADS] = red_d[i];
        }
    }
}

template <int K, int NOUT, int HEADS, int TPB, int AF32>
__global__ __launch_bounds__(TPB) void k_gemm_mfma(
    const void* __restrict__ Ain, const u16* __restrict__ Wp,
    const float* __restrict__ atts, const float* __restrict__ attd,
    u16* __restrict__ Hout, float* __restrict__ as_out, float* __restrict__ ad_out, int M)
{
    gemm_body<K, NOUT, HEADS, TPB, AF32>(blockIdx.x, Ain, Wp, atts, attd, Hout, as_out, ad_out, M);
}

// ---------------- aggregation layer 1: measured-best form (1 edge/iter, 32 VGPR) -----------
__global__ __launch_bounds__(256) void k_agg1(
    const int* __restrict__ row_ptr, const int* __restrict__ col,
    const u16* __restrict__ Hb, const float* __restrict__ as_, const float* __restrict__ ad_,
    const float* __restrict__ bias, u16* __restrict__ outp)
{
    __shared__ int    s_src[4][64];
    __shared__ float4 s_p[4][64];
    int n = blockIdx.x * 4 + (threadIdx.x >> 6);
    if (n >= NN) return;
    const int lane = threadIdx.x & 63;
    const int wv = threadIdx.x >> 6;
    const int head = lane >> 4;                 // channels lane*4..lane*4+3 live in head lane>>4
    float4 ad4 = *(const float4*)(ad_ + (size_t)n * 4);
    int beg = row_ptr[n];
    int cnt = row_ptr[n + 1] - beg + 1;         // +1: self loop first
    float4 sp = make_float4(0.f, 0.f, 0.f, 0.f);
    float ax = 0.f, ay = 0.f, az = 0.f, aw = 0.f;
    for (int c = 0; c < cnt; c += 64) {
        int idx = c + lane;
        int srcl = n;
        float4 p4 = make_float4(0.f, 0.f, 0.f, 0.f);
        if (idx < cnt) {
            srcl = (idx == 0) ? n : col[beg + idx - 1];
            float4 a4 = *(const float4*)(as_ + (size_t)srcl * 4);
            float e;
            e = a4.x + ad4.x; e = e > 0.f ? e : 0.2f * e; p4.x = __expf(e);
            e = a4.y + ad4.y; e = e > 0.f ? e : 0.2f * e; p4.y = __expf(e);
            e = a4.z + ad4.z; e = e > 0.f ? e : 0.2f * e; p4.z = __expf(e);
            e = a4.w + ad4.w; e = e > 0.f ? e : 0.2f * e; p4.w = __expf(e);
        }
        sp.x += p4.x; sp.y += p4.y; sp.z += p4.z; sp.w += p4.w;
        s_src[wv][lane] = srcl;
        s_p[wv][lane] = p4;
        int jmax = min(64, cnt - c);
        #pragma unroll 4
        for (int j = 0; j < jmax; ++j) {
            int srcj = s_src[wv][j];                          // uniform -> broadcast
            float pj = ((const float*)&s_p[wv][j])[head];     // 4 banks, 16-lane broadcast each
            ushort4 hv = *(const ushort4*)(Hb + (size_t)srcj * HC1 + lane * 4);
            ax = fmaf(pj, bf2f(hv.x), ax);
            ay = fmaf(pj, bf2f(hv.y), ay);
            az = fmaf(pj, bf2f(hv.z), az);
            aw = fmaf(pj, bf2f(hv.w), aw);
        }
    }
    #pragma unroll
    for (int off = 1; off < 64; off <<= 1) {
        sp.x += __shfl_xor(sp.x, off);
        sp.y += __shfl_xor(sp.y, off);
        sp.z += __shfl_xor(sp.z, off);
        sp.w += __shfl_xor(sp.w, off);
    }
    float s = head < 2 ? (head == 0 ? sp.x : sp.y) : (head == 2 ? sp.z : sp.w);
    float inv = 1.f / s;
    float4 bv = *(const float4*)(bias + lane * 4);
    float4 o;
    o.x = ax * inv + bv.x;
    o.y = ay * inv + bv.y;
    o.z = az * inv + bv.z;
    o.w = aw * inv + bv.w;
    o.x = o.x > 0.f ? o.x : __expf(o.x) - 1.f;   // ELU
    o.y = o.y > 0.f ? o.y : __expf(o.y) - 1.f;
    o.z = o.z > 0.f ? o.z : __expf(o.z) - 1.f;
    o.w = o.w > 0.f ? o.w : __expf(o.w) - 1.f;
    ushort4 ob;
    ob.x = f2bf(o.x); ob.y = f2bf(o.y); ob.z = f2bf(o.z); ob.w = f2bf(o.w);
    *(ushort4*)(outp + (size_t)n * HC1 + lane * 4) = ob;
}

// ---------------- aggregation layer 2: 2 edges/iter (2x32 lanes), 8B/lane ushort4 gather --------
__global__ __launch_bounds__(256) void k_agg2(
    const int* __restrict__ row_ptr, const int* __restrict__ col,
    const u16* __restrict__ Hb, const float* __restrict__ as_, const float* __restrict__ ad_,
    const float* __restrict__ bias, float* __restrict__ outp)
{
    __shared__ int   s_src[4][64];
    __shared__ float s_p[4][64];
    int n = blockIdx.x * 4 + (threadIdx.x >> 6);
    const int lane = threadIdx.x & 63;
    const int wv = threadIdx.x >> 6;
    const int half = lane >> 5, l32 = lane & 31;
    float ad0 = ad_[n];
    int beg = row_ptr[n];
    int cnt = row_ptr[n + 1] - beg + 1;
    float sp = 0.f;
    float a0 = 0.f, a1 = 0.f, a2 = 0.f, a3 = 0.f;
    for (int c = 0; c < cnt; c += 64) {
        int idx = c + lane;
        int srcl = n;
        float p = 0.f;
        if (idx < cnt) {
            srcl = (idx == 0) ? n : col[beg + idx - 1];
            float e = as_[srcl] + ad0;
            e = e > 0.f ? e : 0.2f * e;
            p = __expf(e);
        }
        sp += p;
        s_src[wv][lane] = srcl;
        s_p[wv][lane] = p;
        int jmax = min(64, cnt - c);
        #pragma unroll 4
        for (int j = 0; j < jmax; j += 2) {
            int jj = j + half;
            int srcj = s_src[wv][jj];
            float pj = s_p[wv][jj];
            ushort4 hv = *(const ushort4*)(Hb + (size_t)srcj * HC2 + l32 * 4);
            a0 = fmaf(pj, bf2f(hv.x), a0);
            a1 = fmaf(pj, bf2f(hv.y), a1);
            a2 = fmaf(pj, bf2f(hv.z), a2);
            a3 = fmaf(pj, bf2f(hv.w), a3);
        }
    }
    a0 += __shfl_xor(a0, 32); a1 += __shfl_xor(a1, 32);
    a2 += __shfl_xor(a2, 32); a3 += __shfl_xor(a3, 32);
    #pragma unroll
    for (int off = 1; off < 64; off <<= 1) sp += __shfl_xor(sp, off);
    if (lane < 32) {
        float inv = 1.f / sp;
        int ch0 = l32 * 4;
        float4 bv = *(const float4*)(bias + ch0);
        float4 o;
        o.x = a0 * inv + bv.x;
        o.y = a1 * inv + bv.y;
        o.z = a2 * inv + bv.z;
        o.w = a3 * inv + bv.w;
        *(float4*)(outp + (size_t)n * HC2 + ch0) = o;
    }
}

// ---------------- launch ----------------
extern "C" void kernel_launch(void* const* d_in, const int* in_sizes, int n_in,
                              void* d_out, int out_size, void* d_ws, size_t ws_size,
                              hipStream_t stream) {
    const float* x   = (const float*)d_in[0];
    const int*       e32 = (const int*)d_in[1];
    const long long* e64 = (const long long*)d_in[1];
    const float* W1  = (const float*)d_in[2];
    const float* as1w = (const float*)d_in[3];
    const float* ad1w = (const float*)d_in[4];
    const float* b1  = (const float*)d_in[5];
    const float* W2  = (const float*)d_in[6];
    const float* as2w = (const float*)d_in[7];
    const float* ad2w = (const float*)d_in[8];
    const float* b2  = (const float*)d_in[9];
    float* out = (float*)d_out;

    char* w = (char*)d_ws;
    auto carve = [&](size_t bytes) -> void* {
        void* p = (void*)w;
        w += (bytes + 255) & ~(size_t)255;
        return p;
    };
    int*   flag    = (int*)carve(4);
    int*   row_ptr = (int*)carve((NN + 1) * sizeof(int));
    int*   cursor  = (int*)carve(NN * sizeof(int));
    int*   col     = (int*)carve(NE * sizeof(int));
    int*   bsum    = (int*)carve(256 * sizeof(int));
    float* as1     = (float*)carve((size_t)NN * H1 * sizeof(float));
    float* ad1     = (float*)carve((size_t)NN * H1 * sizeof(float));
    float* as2     = (float*)carve((size_t)NN * sizeof(float));
    float* ad2     = (float*)carve((size_t)NN * sizeof(float));
    u16*   h1b     = (u16*)carve((size_t)NN * HC1 * sizeof(u16));
    u16*   h2in    = (u16*)carve((size_t)NN * HC1 * sizeof(u16));
    u16*   h2b     = (u16*)carve((size_t)NN * HC2 * sizeof(u16));
    u16*   wp1     = (u16*)carve((size_t)F1 * HC1 * sizeof(u16));
    u16*   wp2     = (u16*)carve((size_t)HC1 * HC2 * sizeof(u16));

    const int TPB = 256;
    const int gAgg = NN / 4;                   // 12500

    // zero degrees (stream-ordered, graph-safe)
    hipMemsetAsync(cursor, 0, NN * sizeof(int), stream);

    // prep (wp1 | wp2 | detect | degree count)
    k_prep<<<257 + GE, 256, 0, stream>>>(W1, W2, wp1, wp2, cursor, e32, e64, flag);

    // CSR scan + fill
    k_part<<<GN, TPB, 0, stream>>>(cursor, bsum);
    k_addb<<<GN, TPB, 0, stream>>>(cursor, bsum, row_ptr, cursor);
    k_fill<<<GE, TPB, 0, stream>>>(e32, e64, flag, cursor, col);

    // layer 1 (gemm reads x f32 directly; stage converts)
    k_gemm_mfma<F1, HC1, H1, 256, 1><<<GM1, 256, 0, stream>>>(
        (const void*)x, wp1, as1w, ad1w, h1b, as1, ad1, NN);
    k_agg1<<<gAgg, TPB, 0, stream>>>(row_ptr, col, h1b, as1, ad1, b1, h2in);

    // layer 2
    k_gemm_mfma<HC1, HC2, 1, 128, 0><<<GM1, 128, 0, stream>>>(
        (const void*)h2in, wp2, as2w, ad2w, h2b, as2, ad2, NN);
    k_agg2<<<gAgg, TPB, 0, stream>>>(row_ptr, col, h2b, as2, ad2, b2, out);
}